// Round 3
// baseline (584.392 us; speedup 1.0000x reference)
//
#include <hip/hip_runtime.h>
#include <hip/hip_fp16.h>
#include <math.h>

// ---------------- precompute: qvec = S@Wq + bq; A[j][h] = (Wk[j,h*32:]·q_h)/sqrt(128); c[h] ----------------
__global__ __launch_bounds__(128) void k_precompute(
    const float* __restrict__ S, const float* __restrict__ Wq, const float* __restrict__ bq,
    const float* __restrict__ Wk, const float* __restrict__ bk,
    float* __restrict__ qvec, float* __restrict__ A, float* __restrict__ cvec) {
  __shared__ float s_S[128];
  __shared__ float s_q[128];
  int j = threadIdx.x;
  s_S[j] = S[j];
  __syncthreads();
  float acc = bq[j];
  for (int i = 0; i < 128; ++i) acc += s_S[i] * Wq[i * 128 + j];
  qvec[j] = acc;
  s_q[j] = acc;
  __syncthreads();
  const float scale = 0.088388347648318447f; // 1/sqrt(128)
  for (int h = 0; h < 4; ++h) {
    float a = 0.f;
    for (int d = 0; d < 32; ++d) a += Wk[j * 128 + h * 32 + d] * s_q[h * 32 + d];
    A[j * 4 + h] = a * scale;
  }
  if (j < 4) {
    float cc = 0.f;
    for (int d = 0; d < 32; ++d) cc += bk[j * 32 + d] * s_q[j * 32 + d];
    cvec[j] = cc * scale;
  }
}

// ---------------- combined histogram: zone counts (points) + col counts (edges) ----------------
__global__ __launch_bounds__(256) void k_hist2(const int* __restrict__ zone, int N,
                                               const int* __restrict__ ecol, int E,
                                               int* __restrict__ counts, int* __restrict__ ecounts) {
  int i = blockIdx.x * blockDim.x + threadIdx.x;
  if (i < N) {
    atomicAdd(&counts[zone[i]], 1);
  } else if (i < N + E) {
    atomicAdd(&ecounts[ecol[i - N]], 1);
  }
}

// ---------------- combined scan: block 0 scans point counts; block 1 scans edge counts + dinv --------
__global__ __launch_bounds__(256) void k_scan2(const int* __restrict__ counts, const int* __restrict__ ecounts,
                                               int R, int* __restrict__ startb, int* __restrict__ estartb,
                                               float* __restrict__ dinv) {
  __shared__ int part[256];
  const int t = threadIdx.x;
  const bool edges = (blockIdx.x == 1);
  const int* __restrict__ cnt = edges ? ecounts : counts;
  int* __restrict__ outp = edges ? estartb : startb;
  int chunk = (R + 255) / 256;
  int b = t * chunk, e = min(b + chunk, R);
  int s = 0;
  for (int i = b; i < e; ++i) s += cnt[i];
  part[t] = s;
  __syncthreads();
  for (int off = 1; off < 256; off <<= 1) {
    int v = (t >= off) ? part[t - off] : 0;
    __syncthreads();
    part[t] += v;
    __syncthreads();
  }
  int run = part[t] - s; // exclusive prefix
  for (int i = b; i < e; ++i) {
    outp[i] = run;
    int c = cnt[i];
    run += c;
    if (edges) dinv[i] = rsqrtf((float)(c + 1)); // +1 self loop
  }
  if (t == 255) outp[R] = part[255];
}

// head-compaction reduce: input s[4] per lane (partials over 4 dims), output = total
// score for head (lane&3), summed over the 32-lane half. 6 shuffles instead of 20.
__device__ __forceinline__ float reduce_heads(const float s0, const float s1,
                                              const float s2, const float s3, int lane) {
  float a01 = (lane & 1) ? s1 : s0;
  float b01 = (lane & 1) ? s0 : s1;
  a01 += __shfl_xor(b01, 1, 64);
  float a23 = (lane & 1) ? s3 : s2;
  float b23 = (lane & 1) ? s2 : s3;
  a23 += __shfl_xor(b23, 1, 64);
  float aa = (lane & 2) ? a23 : a01;
  float bb = (lane & 2) ? a01 : a23;
  aa += __shfl_xor(bb, 2, 64);
  aa += __shfl_xor(aa, 4, 64);
  aa += __shfl_xor(aa, 8, 64);
  aa += __shfl_xor(aa, 16, 64);
  return aa;
}

// ---------------- phase A: stream x, compute p, scatter fp16 row + p into region-sorted order --------
__global__ __launch_bounds__(256) void k_A(
    const float* __restrict__ x, const int* __restrict__ zone,
    const float* __restrict__ A, const float* __restrict__ cvec,
    const int* __restrict__ startb, int* __restrict__ cursor,
    uint2* __restrict__ x16s, float* __restrict__ p_sorted, int N, int chunk) {
  const int tid = threadIdx.x;
  const int wave = tid >> 6, lane = tid & 63;
  const int half = lane >> 5, sl = lane & 31;
  const int d0 = sl * 4;
  float a[4][4];
#pragma unroll
  for (int dd = 0; dd < 4; ++dd)
#pragma unroll
    for (int h = 0; h < 4; ++h) a[dd][h] = A[(d0 + dd) * 4 + h];
  const float cl = cvec[lane & 3];

  const int b0 = blockIdx.x * chunk;
  const int b1 = min(N, b0 + chunk);

  for (int i = b0 + wave * 2 + half; i < b1; i += 16) {
    const int i2 = i + 8;
    const bool v2 = i2 < b1;
    const float4 xv1 = *reinterpret_cast<const float4*>(x + (size_t)i * 128 + d0);
    float4 xv2 = make_float4(0.f, 0.f, 0.f, 0.f);
    int z1 = zone[i], z2 = 0;
    if (v2) {
      xv2 = *reinterpret_cast<const float4*>(x + (size_t)i2 * 128 + d0);
      z2 = zone[i2];
    }
    float s1[4], s2[4];
#pragma unroll
    for (int h = 0; h < 4; ++h) {
      s1[h] = xv1.x * a[0][h] + xv1.y * a[1][h] + xv1.z * a[2][h] + xv1.w * a[3][h];
      s2[h] = xv2.x * a[0][h] + xv2.y * a[1][h] + xv2.z * a[2][h] + xv2.w * a[3][h];
    }
    const float r1 = reduce_heads(s1[0], s1[1], s1[2], s1[3], lane);
    const float r2 = reduce_heads(s2[0], s2[1], s2[2], s2[3], lane);
    const float p1 = __expf(r1 + cl);
    const float p2 = __expf(r2 + cl);

    int pos1 = 0;
    if (sl == 0) pos1 = startb[z1] + atomicAdd(&cursor[z1], 1);
    pos1 = __shfl(pos1, half * 32, 64);
    {
      __half2 h01 = __float22half2_rn(make_float2(xv1.x, xv1.y));
      __half2 h23 = __float22half2_rn(make_float2(xv1.z, xv1.w));
      uint2 u;
      u.x = *reinterpret_cast<unsigned*>(&h01);
      u.y = *reinterpret_cast<unsigned*>(&h23);
      x16s[(size_t)pos1 * 32 + sl] = u;
    }
    if (sl < 4) p_sorted[(size_t)pos1 * 4 + sl] = p1;

    if (v2) {
      int pos2 = 0;
      if (sl == 0) pos2 = startb[z2] + atomicAdd(&cursor[z2], 1);
      pos2 = __shfl(pos2, half * 32, 64);
      {
        __half2 h01 = __float22half2_rn(make_float2(xv2.x, xv2.y));
        __half2 h23 = __float22half2_rn(make_float2(xv2.z, xv2.w));
        uint2 u;
        u.x = *reinterpret_cast<unsigned*>(&h01);
        u.y = *reinterpret_cast<unsigned*>(&h23);
        x16s[(size_t)pos2 * 32 + sl] = u;
      }
      if (sl < 4) p_sorted[(size_t)pos2 * 4 + sl] = p2;
    }
  }
}

// ---------------- edge scatter into CSR by col ----------------
__global__ __launch_bounds__(256) void k_escatter(const int* __restrict__ erow, const int* __restrict__ ecol,
                                                  int E, const int* __restrict__ estartb,
                                                  int* __restrict__ ecursor, int* __restrict__ erow_s) {
  int e = blockIdx.x * blockDim.x + threadIdx.x;
  if (e < E) {
    int c = ecol[e];
    int pos = estartb[c] + atomicAdd(&ecursor[c], 1);
    erow_s[pos] = erow[e];
  }
}

// ---------------- phase B: streaming per-region weighted accumulate (coalesced fp16 rows) ----------------
__global__ __launch_bounds__(256) void k_B(
    const uint2* __restrict__ x16s, const int* __restrict__ startb,
    const float* __restrict__ p_sorted,
    float* __restrict__ Xagg, float* __restrict__ denom) {
  const int r = blockIdx.x;
  const int s0 = startb[r], s1 = startb[r + 1];
  const int tid = threadIdx.x;
  const int wave = tid >> 6, lane = tid & 63;
  const int half = lane >> 5, sl = lane & 31;
  const int d0 = sl * 4;

  float xagg[4][4] = {};
  float dsum[4] = {};

#pragma unroll 2
  for (int j = s0 + wave * 2 + half; j < s1; j += 8) {
    const uint2 u = x16s[(size_t)j * 32 + sl];
    const __half2 h01 = *reinterpret_cast<const __half2*>(&u.x);
    const __half2 h23 = *reinterpret_cast<const __half2*>(&u.y);
    const float2 f01 = __half22float2(h01);
    const float2 f23 = __half22float2(h23);
    const float4 q = *reinterpret_cast<const float4*>(p_sorted + (size_t)j * 4);
    xagg[0][0] += q.x * f01.x; xagg[0][1] += q.y * f01.x; xagg[0][2] += q.z * f01.x; xagg[0][3] += q.w * f01.x;
    xagg[1][0] += q.x * f01.y; xagg[1][1] += q.y * f01.y; xagg[1][2] += q.z * f01.y; xagg[1][3] += q.w * f01.y;
    xagg[2][0] += q.x * f23.x; xagg[2][1] += q.y * f23.x; xagg[2][2] += q.z * f23.x; xagg[2][3] += q.w * f23.x;
    xagg[3][0] += q.x * f23.y; xagg[3][1] += q.y * f23.y; xagg[3][2] += q.z * f23.y; xagg[3][3] += q.w * f23.y;
    dsum[0] += q.x; dsum[1] += q.y; dsum[2] += q.z; dsum[3] += q.w;
  }

  __shared__ float s_xagg[512]; // [dim][h] layout: dim*4+h
  __shared__ float s_den[4];
  for (int t = tid; t < 512; t += 256) s_xagg[t] = 0.f;
  if (tid < 4) s_den[tid] = 0.f;
  __syncthreads();
#pragma unroll
  for (int dd = 0; dd < 4; ++dd)
#pragma unroll
    for (int h = 0; h < 4; ++h) atomicAdd(&s_xagg[(d0 + dd) * 4 + h], xagg[dd][h]);
  if (sl == 0) {
#pragma unroll
    for (int h = 0; h < 4; ++h) atomicAdd(&s_den[h], dsum[h]);
  }
  __syncthreads();
  for (int t = tid; t < 512; t += 256) {
    int h = t >> 7, j = t & 127;
    Xagg[(size_t)r * 512 + t] = s_xagg[j * 4 + h];
  }
  if (tid < 4) denom[r * 4 + tid] = s_den[tid];
}

// ---------------- batched epilogue: attn -> O -> O+relu(O@Wo+bo) -> h = O2@Wg  (8 regions/block) --------
__global__ __launch_bounds__(256) void k_epilogue(
    const float* __restrict__ Xagg, const float* __restrict__ denom, const float* __restrict__ qvec,
    const float* __restrict__ Wv, const float* __restrict__ bv,
    const float* __restrict__ Wo, const float* __restrict__ bo,
    const float* __restrict__ Wg, float* __restrict__ hout, int R) {
  const int r0 = blockIdx.x * 8;
  const int tid = threadIdx.x;
  __shared__ float s_xa[8 * 512];
  __shared__ float s_den[8 * 4];
  __shared__ float s_O[8 * 128];
  __shared__ float s_O2[8 * 128];

  for (int t = tid; t < 8 * 512; t += 256) {
    int rl = t >> 9;
    s_xa[t] = (r0 + rl < R) ? Xagg[(size_t)r0 * 512 + t] : 0.f;
  }
  if (tid < 32) {
    int rl = tid >> 2;
    s_den[tid] = (r0 + rl < R) ? denom[r0 * 4 + tid] : 1.f;
  }
  __syncthreads();

  for (int o = tid; o < 1024; o += 256) {
    int rl = o >> 7, t = o & 127, h = t >> 5;
    float acc = 0.f;
    const float* xa = &s_xa[rl * 512 + h * 128];
    for (int j = 0; j < 128; j += 4) {
      float4 x4 = *reinterpret_cast<const float4*>(xa + j);
      acc += x4.x * Wv[j * 128 + t] + x4.y * Wv[(j + 1) * 128 + t]
           + x4.z * Wv[(j + 2) * 128 + t] + x4.w * Wv[(j + 3) * 128 + t];
    }
    float dn = s_den[rl * 4 + h];
    float attn = (acc + dn * bv[t]) / fmaxf(dn, 1e-9f);
    s_O[o] = qvec[t] + attn;
  }
  __syncthreads();

  for (int o = tid; o < 1024; o += 256) {
    int rl = o >> 7, t = o & 127;
    float acc = bo[t];
    const float* ov = &s_O[rl * 128];
    for (int j = 0; j < 128; j += 4) {
      float4 x4 = *reinterpret_cast<const float4*>(ov + j);
      acc += x4.x * Wo[j * 128 + t] + x4.y * Wo[(j + 1) * 128 + t]
           + x4.z * Wo[(j + 2) * 128 + t] + x4.w * Wo[(j + 3) * 128 + t];
    }
    s_O2[o] = s_O[o] + fmaxf(acc, 0.f);
  }
  __syncthreads();

  for (int o = tid; o < 1024; o += 256) {
    int rl = o >> 7, t = o & 127;
    float acc = 0.f;
    const float* ov = &s_O2[rl * 128];
    for (int j = 0; j < 128; j += 4) {
      float4 x4 = *reinterpret_cast<const float4*>(ov + j);
      acc += x4.x * Wg[j * 128 + t] + x4.y * Wg[(j + 1) * 128 + t]
           + x4.z * Wg[(j + 2) * 128 + t] + x4.w * Wg[(j + 3) * 128 + t];
    }
    if (r0 + rl < R) hout[(size_t)(r0 + rl) * 128 + t] = acc;
  }
}

// ---------------- fused GCN: self-loop + CSR edge gather + bias + PReLU (wave per region) ----------------
__global__ __launch_bounds__(256) void k_gcn(
    const int* __restrict__ estartb, const int* __restrict__ erow_s,
    const float* __restrict__ dinv, const float* __restrict__ hbuf,
    const float* __restrict__ bg, const float* __restrict__ pw,
    float* __restrict__ out, int R) {
  const int r = blockIdx.x * 4 + (threadIdx.x >> 6);
  if (r >= R) return;
  const int lane = threadIdx.x & 63;
  const int d0 = lane * 2;
  const float dr = dinv[r];
  const float2 hc = *reinterpret_cast<const float2*>(hbuf + (size_t)r * 128 + d0);
  float accx = dr * dr * hc.x;
  float accy = dr * dr * hc.y;
  const int e0 = estartb[r], e1 = estartb[r + 1];
  for (int e = e0; e < e1; ++e) {
    const int rr = erow_s[e];
    const float w = dinv[rr] * dr;
    const float2 hv = *reinterpret_cast<const float2*>(hbuf + (size_t)rr * 128 + d0);
    accx += w * hv.x;
    accy += w * hv.y;
  }
  const float2 b = *reinterpret_cast<const float2*>(bg + d0);
  const float2 pv = *reinterpret_cast<const float2*>(pw + d0);
  const float t0 = accx + b.x;
  const float t1 = accy + b.y;
  out[(size_t)r * 128 + d0]     = (t0 >= 0.f) ? t0 : pv.x * t0;
  out[(size_t)r * 128 + d0 + 1] = (t1 >= 0.f) ? t1 : pv.y * t1;
}

// ---------------- host ----------------
extern "C" void kernel_launch(void* const* d_in, const int* in_sizes, int n_in,
                              void* d_out, int out_size, void* d_ws, size_t ws_size,
                              hipStream_t stream) {
  const float* x   = (const float*)d_in[0];
  const int*   zone = (const int*)d_in[1];
  const int*   eidx = (const int*)d_in[2];
  const float* S   = (const float*)d_in[4];
  const float* Wq  = (const float*)d_in[5];
  const float* bq  = (const float*)d_in[6];
  const float* Wk  = (const float*)d_in[7];
  const float* bk  = (const float*)d_in[8];
  const float* Wv  = (const float*)d_in[9];
  const float* bv  = (const float*)d_in[10];
  const float* Wo  = (const float*)d_in[11];
  const float* bo  = (const float*)d_in[12];
  const float* Wg  = (const float*)d_in[13];
  const float* bg  = (const float*)d_in[14];
  const float* pw  = (const float*)d_in[15];
  float* out = (float*)d_out;

  const int N = in_sizes[0] / 128;
  const int E = in_sizes[2] / 2;
  const int R = out_size / 128;
  const int* erow = eidx;
  const int* ecol = eidx + E;

  char* wsb = (char*)d_ws;
  size_t off = 0;
  auto alloc = [&](size_t bytes) -> void* {
    void* p = wsb + off;
    off = (off + bytes + 255) & ~(size_t)255;
    return p;
  };
  // zeroed int block: counts | cursor | ecounts | ecursor  (single memset)
  int* izero  = (int*)alloc((size_t)4 * R * 4);
  int* counts = izero;
  int* cursor = izero + R;
  int* ecounts= izero + 2 * R;
  int* ecursor= izero + 3 * R;

  float* qvec  = (float*)alloc(128 * 4);
  float* A     = (float*)alloc(512 * 4);
  float* cvec  = (float*)alloc(4 * 4);
  int*   startb = (int*)alloc((size_t)(R + 1) * 4);
  int*   estartb= (int*)alloc((size_t)(R + 1) * 4);
  float* dinv  = (float*)alloc((size_t)R * 4);
  int*   erow_s= (int*)alloc((size_t)E * 4);
  float* p_sorted = (float*)alloc((size_t)N * 4 * 4);
  float* Xagg  = (float*)alloc((size_t)R * 512 * 4);
  float* denom = (float*)alloc((size_t)R * 4 * 4);
  float* hbuf  = (float*)alloc((size_t)R * 128 * 4);
  uint2* x16s  = (uint2*)alloc((size_t)N * 256); // N rows of 128 fp16 = 256B each

  hipMemsetAsync(izero, 0, (size_t)4 * R * 4, stream);

  k_precompute<<<1, 128, 0, stream>>>(S, Wq, bq, Wk, bk, qvec, A, cvec);
  k_hist2<<<(N + E + 255) / 256, 256, 0, stream>>>(zone, N, ecol, E, counts, ecounts);
  k_scan2<<<2, 256, 0, stream>>>(counts, ecounts, R, startb, estartb, dinv);
  const int NB = 2048;
  const int chunk = (((N + NB - 1) / NB) + 15) & ~15;
  k_A<<<NB, 256, 0, stream>>>(x, zone, A, cvec, startb, cursor, x16s, p_sorted, N, chunk);
  k_escatter<<<(E + 255) / 256, 256, 0, stream>>>(erow, ecol, E, estartb, ecursor, erow_s);
  k_B<<<R, 256, 0, stream>>>(x16s, startb, p_sorted, Xagg, denom);
  k_epilogue<<<(R + 7) / 8, 256, 0, stream>>>(Xagg, denom, qvec, Wv, bv, Wo, bo, Wg, hbuf, R);
  k_gcn<<<(R + 3) / 4, 256, 0, stream>>>(estartb, erow_s, dinv, hbuf, bg, pw, out, R);
}

// Round 4
// 583.454 us; speedup vs baseline: 1.0016x; 1.0016x over previous
//
#include <hip/hip_runtime.h>
#include <hip/hip_fp16.h>
#include <math.h>

// ---------------- zero the counter block (replaces hipMemsetAsync: captured memset
// nodes cost ~300us/replay in-graph on this runtime) ----------------
__global__ __launch_bounds__(256) void k_zero(int* __restrict__ p, int n4) {
  int i = blockIdx.x * blockDim.x + threadIdx.x;
  if (i < n4) reinterpret_cast<int4*>(p)[i] = make_int4(0, 0, 0, 0);
}

// ---------------- precompute: qvec = S@Wq + bq; A[j][h] = (Wk[j,h*32:]·q_h)/sqrt(128); c[h] ----------------
__global__ __launch_bounds__(128) void k_precompute(
    const float* __restrict__ S, const float* __restrict__ Wq, const float* __restrict__ bq,
    const float* __restrict__ Wk, const float* __restrict__ bk,
    float* __restrict__ qvec, float* __restrict__ A, float* __restrict__ cvec) {
  __shared__ float s_S[128];
  __shared__ float s_q[128];
  int j = threadIdx.x;
  s_S[j] = S[j];
  __syncthreads();
  float acc = bq[j];
  for (int i = 0; i < 128; ++i) acc += s_S[i] * Wq[i * 128 + j];
  qvec[j] = acc;
  s_q[j] = acc;
  __syncthreads();
  const float scale = 0.088388347648318447f; // 1/sqrt(128)
  for (int h = 0; h < 4; ++h) {
    float a = 0.f;
    for (int d = 0; d < 32; ++d) a += Wk[j * 128 + h * 32 + d] * s_q[h * 32 + d];
    A[j * 4 + h] = a * scale;
  }
  if (j < 4) {
    float cc = 0.f;
    for (int d = 0; d < 32; ++d) cc += bk[j * 32 + d] * s_q[j * 32 + d];
    cvec[j] = cc * scale;
  }
}

// ---------------- combined histogram: zone counts (points) + col counts (edges) ----------------
__global__ __launch_bounds__(256) void k_hist2(const int* __restrict__ zone, int N,
                                               const int* __restrict__ ecol, int E,
                                               int* __restrict__ counts, int* __restrict__ ecounts) {
  int i = blockIdx.x * blockDim.x + threadIdx.x;
  if (i < N) {
    atomicAdd(&counts[zone[i]], 1);
  } else if (i < N + E) {
    atomicAdd(&ecounts[ecol[i - N]], 1);
  }
}

// ---------------- combined scan: block 0 scans point counts; block 1 scans edge counts + dinv --------
__global__ __launch_bounds__(256) void k_scan2(const int* __restrict__ counts, const int* __restrict__ ecounts,
                                               int R, int* __restrict__ startb, int* __restrict__ estartb,
                                               float* __restrict__ dinv) {
  __shared__ int part[256];
  const int t = threadIdx.x;
  const bool edges = (blockIdx.x == 1);
  const int* __restrict__ cnt = edges ? ecounts : counts;
  int* __restrict__ outp = edges ? estartb : startb;
  int chunk = (R + 255) / 256;
  int b = t * chunk, e = min(b + chunk, R);
  int s = 0;
  for (int i = b; i < e; ++i) s += cnt[i];
  part[t] = s;
  __syncthreads();
  for (int off = 1; off < 256; off <<= 1) {
    int v = (t >= off) ? part[t - off] : 0;
    __syncthreads();
    part[t] += v;
    __syncthreads();
  }
  int run = part[t] - s; // exclusive prefix
  for (int i = b; i < e; ++i) {
    outp[i] = run;
    int c = cnt[i];
    run += c;
    if (edges) dinv[i] = rsqrtf((float)(c + 1)); // +1 self loop
  }
  if (t == 255) outp[R] = part[255];
}

// head-compaction reduce: input s[4] per lane (partials over 4 dims), output = total
// score for head (lane&3), summed over the 32-lane half. 6 shuffles instead of 20.
__device__ __forceinline__ float reduce_heads(const float s0, const float s1,
                                              const float s2, const float s3, int lane) {
  float a01 = (lane & 1) ? s1 : s0;
  float b01 = (lane & 1) ? s0 : s1;
  a01 += __shfl_xor(b01, 1, 64);
  float a23 = (lane & 1) ? s3 : s2;
  float b23 = (lane & 1) ? s2 : s3;
  a23 += __shfl_xor(b23, 1, 64);
  float aa = (lane & 2) ? a23 : a01;
  float bb = (lane & 2) ? a01 : a23;
  aa += __shfl_xor(bb, 2, 64);
  aa += __shfl_xor(aa, 4, 64);
  aa += __shfl_xor(aa, 8, 64);
  aa += __shfl_xor(aa, 16, 64);
  return aa;
}

// ---------------- phase A: stream x, compute p, scatter fp16 row + p into region-sorted order --------
__global__ __launch_bounds__(256) void k_A(
    const float* __restrict__ x, const int* __restrict__ zone,
    const float* __restrict__ A, const float* __restrict__ cvec,
    const int* __restrict__ startb, int* __restrict__ cursor,
    uint2* __restrict__ x16s, float* __restrict__ p_sorted, int N, int chunk) {
  const int tid = threadIdx.x;
  const int wave = tid >> 6, lane = tid & 63;
  const int half = lane >> 5, sl = lane & 31;
  const int d0 = sl * 4;
  float a[4][4];
#pragma unroll
  for (int dd = 0; dd < 4; ++dd)
#pragma unroll
    for (int h = 0; h < 4; ++h) a[dd][h] = A[(d0 + dd) * 4 + h];
  const float cl = cvec[lane & 3];

  const int b0 = blockIdx.x * chunk;
  const int b1 = min(N, b0 + chunk);

  for (int i = b0 + wave * 2 + half; i < b1; i += 16) {
    const int i2 = i + 8;
    const bool v2 = i2 < b1;
    const float4 xv1 = *reinterpret_cast<const float4*>(x + (size_t)i * 128 + d0);
    float4 xv2 = make_float4(0.f, 0.f, 0.f, 0.f);
    int z1 = zone[i], z2 = 0;
    if (v2) {
      xv2 = *reinterpret_cast<const float4*>(x + (size_t)i2 * 128 + d0);
      z2 = zone[i2];
    }
    float s1[4], s2[4];
#pragma unroll
    for (int h = 0; h < 4; ++h) {
      s1[h] = xv1.x * a[0][h] + xv1.y * a[1][h] + xv1.z * a[2][h] + xv1.w * a[3][h];
      s2[h] = xv2.x * a[0][h] + xv2.y * a[1][h] + xv2.z * a[2][h] + xv2.w * a[3][h];
    }
    const float r1 = reduce_heads(s1[0], s1[1], s1[2], s1[3], lane);
    const float r2 = reduce_heads(s2[0], s2[1], s2[2], s2[3], lane);
    const float p1 = __expf(r1 + cl);
    const float p2 = __expf(r2 + cl);

    int pos1 = 0;
    if (sl == 0) pos1 = startb[z1] + atomicAdd(&cursor[z1], 1);
    pos1 = __shfl(pos1, half * 32, 64);
    {
      __half2 h01 = __float22half2_rn(make_float2(xv1.x, xv1.y));
      __half2 h23 = __float22half2_rn(make_float2(xv1.z, xv1.w));
      uint2 u;
      u.x = *reinterpret_cast<unsigned*>(&h01);
      u.y = *reinterpret_cast<unsigned*>(&h23);
      x16s[(size_t)pos1 * 32 + sl] = u;
    }
    if (sl < 4) p_sorted[(size_t)pos1 * 4 + sl] = p1;

    if (v2) {
      int pos2 = 0;
      if (sl == 0) pos2 = startb[z2] + atomicAdd(&cursor[z2], 1);
      pos2 = __shfl(pos2, half * 32, 64);
      {
        __half2 h01 = __float22half2_rn(make_float2(xv2.x, xv2.y));
        __half2 h23 = __float22half2_rn(make_float2(xv2.z, xv2.w));
        uint2 u;
        u.x = *reinterpret_cast<unsigned*>(&h01);
        u.y = *reinterpret_cast<unsigned*>(&h23);
        x16s[(size_t)pos2 * 32 + sl] = u;
      }
      if (sl < 4) p_sorted[(size_t)pos2 * 4 + sl] = p2;
    }
  }
}

// ---------------- edge scatter into CSR by col ----------------
__global__ __launch_bounds__(256) void k_escatter(const int* __restrict__ erow, const int* __restrict__ ecol,
                                                  int E, const int* __restrict__ estartb,
                                                  int* __restrict__ ecursor, int* __restrict__ erow_s) {
  int e = blockIdx.x * blockDim.x + threadIdx.x;
  if (e < E) {
    int c = ecol[e];
    int pos = estartb[c] + atomicAdd(&ecursor[c], 1);
    erow_s[pos] = erow[e];
  }
}

// ---------------- phase B: streaming per-region weighted accumulate (coalesced fp16 rows) ----------------
__global__ __launch_bounds__(256) void k_B(
    const uint2* __restrict__ x16s, const int* __restrict__ startb,
    const float* __restrict__ p_sorted,
    float* __restrict__ Xagg, float* __restrict__ denom) {
  const int r = blockIdx.x;
  const int s0 = startb[r], s1 = startb[r + 1];
  const int tid = threadIdx.x;
  const int wave = tid >> 6, lane = tid & 63;
  const int half = lane >> 5, sl = lane & 31;
  const int d0 = sl * 4;

  float xagg[4][4] = {};
  float dsum[4] = {};

#pragma unroll 2
  for (int j = s0 + wave * 2 + half; j < s1; j += 8) {
    const uint2 u = x16s[(size_t)j * 32 + sl];
    const __half2 h01 = *reinterpret_cast<const __half2*>(&u.x);
    const __half2 h23 = *reinterpret_cast<const __half2*>(&u.y);
    const float2 f01 = __half22float2(h01);
    const float2 f23 = __half22float2(h23);
    const float4 q = *reinterpret_cast<const float4*>(p_sorted + (size_t)j * 4);
    xagg[0][0] += q.x * f01.x; xagg[0][1] += q.y * f01.x; xagg[0][2] += q.z * f01.x; xagg[0][3] += q.w * f01.x;
    xagg[1][0] += q.x * f01.y; xagg[1][1] += q.y * f01.y; xagg[1][2] += q.z * f01.y; xagg[1][3] += q.w * f01.y;
    xagg[2][0] += q.x * f23.x; xagg[2][1] += q.y * f23.x; xagg[2][2] += q.z * f23.x; xagg[2][3] += q.w * f23.x;
    xagg[3][0] += q.x * f23.y; xagg[3][1] += q.y * f23.y; xagg[3][2] += q.z * f23.y; xagg[3][3] += q.w * f23.y;
    dsum[0] += q.x; dsum[1] += q.y; dsum[2] += q.z; dsum[3] += q.w;
  }

  __shared__ float s_xagg[512]; // [dim][h] layout: dim*4+h
  __shared__ float s_den[4];
  for (int t = tid; t < 512; t += 256) s_xagg[t] = 0.f;
  if (tid < 4) s_den[tid] = 0.f;
  __syncthreads();
#pragma unroll
  for (int dd = 0; dd < 4; ++dd)
#pragma unroll
    for (int h = 0; h < 4; ++h) atomicAdd(&s_xagg[(d0 + dd) * 4 + h], xagg[dd][h]);
  if (sl == 0) {
#pragma unroll
    for (int h = 0; h < 4; ++h) atomicAdd(&s_den[h], dsum[h]);
  }
  __syncthreads();
  for (int t = tid; t < 512; t += 256) {
    int h = t >> 7, j = t & 127;
    Xagg[(size_t)r * 512 + t] = s_xagg[j * 4 + h];
  }
  if (tid < 4) denom[r * 4 + tid] = s_den[tid];
}

// ---------------- batched epilogue: attn -> O -> O+relu(O@Wo+bo) -> h = O2@Wg  (8 regions/block) --------
__global__ __launch_bounds__(256) void k_epilogue(
    const float* __restrict__ Xagg, const float* __restrict__ denom, const float* __restrict__ qvec,
    const float* __restrict__ Wv, const float* __restrict__ bv,
    const float* __restrict__ Wo, const float* __restrict__ bo,
    const float* __restrict__ Wg, float* __restrict__ hout, int R) {
  const int r0 = blockIdx.x * 8;
  const int tid = threadIdx.x;
  __shared__ float s_xa[8 * 512];
  __shared__ float s_den[8 * 4];
  __shared__ float s_O[8 * 128];
  __shared__ float s_O2[8 * 128];

  for (int t = tid; t < 8 * 512; t += 256) {
    int rl = t >> 9;
    s_xa[t] = (r0 + rl < R) ? Xagg[(size_t)r0 * 512 + t] : 0.f;
  }
  if (tid < 32) {
    int rl = tid >> 2;
    s_den[tid] = (r0 + rl < R) ? denom[r0 * 4 + tid] : 1.f;
  }
  __syncthreads();

  for (int o = tid; o < 1024; o += 256) {
    int rl = o >> 7, t = o & 127, h = t >> 5;
    float acc = 0.f;
    const float* xa = &s_xa[rl * 512 + h * 128];
    for (int j = 0; j < 128; j += 4) {
      float4 x4 = *reinterpret_cast<const float4*>(xa + j);
      acc += x4.x * Wv[j * 128 + t] + x4.y * Wv[(j + 1) * 128 + t]
           + x4.z * Wv[(j + 2) * 128 + t] + x4.w * Wv[(j + 3) * 128 + t];
    }
    float dn = s_den[rl * 4 + h];
    float attn = (acc + dn * bv[t]) / fmaxf(dn, 1e-9f);
    s_O[o] = qvec[t] + attn;
  }
  __syncthreads();

  for (int o = tid; o < 1024; o += 256) {
    int rl = o >> 7, t = o & 127;
    float acc = bo[t];
    const float* ov = &s_O[rl * 128];
    for (int j = 0; j < 128; j += 4) {
      float4 x4 = *reinterpret_cast<const float4*>(ov + j);
      acc += x4.x * Wo[j * 128 + t] + x4.y * Wo[(j + 1) * 128 + t]
           + x4.z * Wo[(j + 2) * 128 + t] + x4.w * Wo[(j + 3) * 128 + t];
    }
    s_O2[o] = s_O[o] + fmaxf(acc, 0.f);
  }
  __syncthreads();

  for (int o = tid; o < 1024; o += 256) {
    int rl = o >> 7, t = o & 127;
    float acc = 0.f;
    const float* ov = &s_O2[rl * 128];
    for (int j = 0; j < 128; j += 4) {
      float4 x4 = *reinterpret_cast<const float4*>(ov + j);
      acc += x4.x * Wg[j * 128 + t] + x4.y * Wg[(j + 1) * 128 + t]
           + x4.z * Wg[(j + 2) * 128 + t] + x4.w * Wg[(j + 3) * 128 + t];
    }
    if (r0 + rl < R) hout[(size_t)(r0 + rl) * 128 + t] = acc;
  }
}

// ---------------- fused GCN: self-loop + CSR edge gather + bias + PReLU (wave per region) ----------------
__global__ __launch_bounds__(256) void k_gcn(
    const int* __restrict__ estartb, const int* __restrict__ erow_s,
    const float* __restrict__ dinv, const float* __restrict__ hbuf,
    const float* __restrict__ bg, const float* __restrict__ pw,
    float* __restrict__ out, int R) {
  const int r = blockIdx.x * 4 + (threadIdx.x >> 6);
  if (r >= R) return;
  const int lane = threadIdx.x & 63;
  const int d0 = lane * 2;
  const float dr = dinv[r];
  const float2 hc = *reinterpret_cast<const float2*>(hbuf + (size_t)r * 128 + d0);
  float accx = dr * dr * hc.x;
  float accy = dr * dr * hc.y;
  const int e0 = estartb[r], e1 = estartb[r + 1];
  for (int e = e0; e < e1; ++e) {
    const int rr = erow_s[e];
    const float w = dinv[rr] * dr;
    const float2 hv = *reinterpret_cast<const float2*>(hbuf + (size_t)rr * 128 + d0);
    accx += w * hv.x;
    accy += w * hv.y;
  }
  const float2 b = *reinterpret_cast<const float2*>(bg + d0);
  const float2 pv = *reinterpret_cast<const float2*>(pw + d0);
  const float t0 = accx + b.x;
  const float t1 = accy + b.y;
  out[(size_t)r * 128 + d0]     = (t0 >= 0.f) ? t0 : pv.x * t0;
  out[(size_t)r * 128 + d0 + 1] = (t1 >= 0.f) ? t1 : pv.y * t1;
}

// ---------------- host ----------------
extern "C" void kernel_launch(void* const* d_in, const int* in_sizes, int n_in,
                              void* d_out, int out_size, void* d_ws, size_t ws_size,
                              hipStream_t stream) {
  const float* x   = (const float*)d_in[0];
  const int*   zone = (const int*)d_in[1];
  const int*   eidx = (const int*)d_in[2];
  const float* S   = (const float*)d_in[4];
  const float* Wq  = (const float*)d_in[5];
  const float* bq  = (const float*)d_in[6];
  const float* Wk  = (const float*)d_in[7];
  const float* bk  = (const float*)d_in[8];
  const float* Wv  = (const float*)d_in[9];
  const float* bv  = (const float*)d_in[10];
  const float* Wo  = (const float*)d_in[11];
  const float* bo  = (const float*)d_in[12];
  const float* Wg  = (const float*)d_in[13];
  const float* bg  = (const float*)d_in[14];
  const float* pw  = (const float*)d_in[15];
  float* out = (float*)d_out;

  const int N = in_sizes[0] / 128;
  const int E = in_sizes[2] / 2;
  const int R = out_size / 128;
  const int* erow = eidx;
  const int* ecol = eidx + E;

  char* wsb = (char*)d_ws;
  size_t off = 0;
  auto alloc = [&](size_t bytes) -> void* {
    void* p = wsb + off;
    off = (off + bytes + 255) & ~(size_t)255;
    return p;
  };
  // zeroed int block: counts | cursor | ecounts | ecursor  (zeroed by k_zero, NOT memset)
  int* izero  = (int*)alloc((size_t)4 * R * 4);
  int* counts = izero;
  int* cursor = izero + R;
  int* ecounts= izero + 2 * R;
  int* ecursor= izero + 3 * R;

  float* qvec  = (float*)alloc(128 * 4);
  float* A     = (float*)alloc(512 * 4);
  float* cvec  = (float*)alloc(4 * 4);
  int*   startb = (int*)alloc((size_t)(R + 1) * 4);
  int*   estartb= (int*)alloc((size_t)(R + 1) * 4);
  float* dinv  = (float*)alloc((size_t)R * 4);
  int*   erow_s= (int*)alloc((size_t)E * 4);
  float* p_sorted = (float*)alloc((size_t)N * 4 * 4);
  float* Xagg  = (float*)alloc((size_t)R * 512 * 4);
  float* denom = (float*)alloc((size_t)R * 4 * 4);
  float* hbuf  = (float*)alloc((size_t)R * 128 * 4);
  uint2* x16s  = (uint2*)alloc((size_t)N * 256); // N rows of 128 fp16 = 256B each

  const int n4 = R; // 4*R ints = R int4s
  k_zero<<<(n4 + 255) / 256, 256, 0, stream>>>(izero, n4);
  k_precompute<<<1, 128, 0, stream>>>(S, Wq, bq, Wk, bk, qvec, A, cvec);
  k_hist2<<<(N + E + 255) / 256, 256, 0, stream>>>(zone, N, ecol, E, counts, ecounts);
  k_scan2<<<2, 256, 0, stream>>>(counts, ecounts, R, startb, estartb, dinv);
  const int NB = 2048;
  const int chunk = (((N + NB - 1) / NB) + 15) & ~15;
  k_A<<<NB, 256, 0, stream>>>(x, zone, A, cvec, startb, cursor, x16s, p_sorted, N, chunk);
  k_escatter<<<(E + 255) / 256, 256, 0, stream>>>(erow, ecol, E, estartb, ecursor, erow_s);
  k_B<<<R, 256, 0, stream>>>(x16s, startb, p_sorted, Xagg, denom);
  k_epilogue<<<(R + 7) / 8, 256, 0, stream>>>(Xagg, denom, qvec, Wv, bv, Wo, bo, Wg, hbuf, R);
  k_gcn<<<(R + 3) / 4, 256, 0, stream>>>(estartb, erow_s, dinv, hbuf, bg, pw, out, R);
}

// Round 6
// 540.237 us; speedup vs baseline: 1.0817x; 1.0800x over previous
//
#include <hip/hip_runtime.h>
#include <math.h>

// ---------------- zero the counter block ----------------
__global__ __launch_bounds__(256) void k_zero(int* __restrict__ p, int n4) {
  int i = blockIdx.x * blockDim.x + threadIdx.x;
  if (i < n4) reinterpret_cast<int4*>(p)[i] = make_int4(0, 0, 0, 0);
}

// ---------------- precompute: qvec = S@Wq + bq; A[j][h] = (Wk[j,h*32:]·q_h)/sqrt(128); c[h] ----------------
__global__ __launch_bounds__(128) void k_precompute(
    const float* __restrict__ S, const float* __restrict__ Wq, const float* __restrict__ bq,
    const float* __restrict__ Wk, const float* __restrict__ bk,
    float* __restrict__ qvec, float* __restrict__ A, float* __restrict__ cvec) {
  __shared__ float s_S[128];
  __shared__ float s_q[128];
  int j = threadIdx.x;
  s_S[j] = S[j];
  __syncthreads();
  float acc = bq[j];
  for (int i = 0; i < 128; ++i) acc += s_S[i] * Wq[i * 128 + j];
  qvec[j] = acc;
  s_q[j] = acc;
  __syncthreads();
  const float scale = 0.088388347648318447f; // 1/sqrt(128)
  for (int h = 0; h < 4; ++h) {
    float a = 0.f;
    for (int d = 0; d < 32; ++d) a += Wk[j * 128 + h * 32 + d] * s_q[h * 32 + d];
    A[j * 4 + h] = a * scale;
  }
  if (j < 4) {
    float cc = 0.f;
    for (int d = 0; d < 32; ++d) cc += bk[j * 32 + d] * s_q[j * 32 + d];
    cvec[j] = cc * scale;
  }
}

// ---------------- combined histogram: zone counts (points) + col counts (edges) ----------------
__global__ __launch_bounds__(256) void k_hist2(const int* __restrict__ zone, int N,
                                               const int* __restrict__ ecol, int E,
                                               int* __restrict__ counts, int* __restrict__ ecounts) {
  int i = blockIdx.x * blockDim.x + threadIdx.x;
  if (i < N) {
    atomicAdd(&counts[zone[i]], 1);
  } else if (i < N + E) {
    atomicAdd(&ecounts[ecol[i - N]], 1);
  }
}

// ---------------- combined scan: block 0 scans point counts; block 1 scans edge counts + dinv --------
__global__ __launch_bounds__(256) void k_scan2(const int* __restrict__ counts, const int* __restrict__ ecounts,
                                               int R, int* __restrict__ startb, int* __restrict__ estartb,
                                               float* __restrict__ dinv) {
  __shared__ int part[256];
  const int t = threadIdx.x;
  const bool edges = (blockIdx.x == 1);
  const int* __restrict__ cnt = edges ? ecounts : counts;
  int* __restrict__ outp = edges ? estartb : startb;
  int chunk = (R + 255) / 256;
  int b = t * chunk, e = min(b + chunk, R);
  int s = 0;
  for (int i = b; i < e; ++i) s += cnt[i];
  part[t] = s;
  __syncthreads();
  for (int off = 1; off < 256; off <<= 1) {
    int v = (t >= off) ? part[t - off] : 0;
    __syncthreads();
    part[t] += v;
    __syncthreads();
  }
  int run = part[t] - s; // exclusive prefix
  for (int i = b; i < e; ++i) {
    outp[i] = run;
    int c = cnt[i];
    run += c;
    if (edges) dinv[i] = rsqrtf((float)(c + 1)); // +1 self loop
  }
  if (t == 255) outp[R] = part[255];
}

// ---------------- merged scatter: point indices by zone, edge rows by col ----------------
__global__ __launch_bounds__(256) void k_scatter2(
    const int* __restrict__ zone, int N,
    const int* __restrict__ erow, const int* __restrict__ ecol, int E,
    const int* __restrict__ startb, int* __restrict__ cursor, int* __restrict__ perm,
    const int* __restrict__ estartb, int* __restrict__ ecursor, int* __restrict__ erow_s) {
  int i = blockIdx.x * blockDim.x + threadIdx.x;
  if (i < N) {
    int r = zone[i];
    perm[startb[r] + atomicAdd(&cursor[r], 1)] = i;
  } else if (i < N + E) {
    int e = i - N;
    int c = ecol[e];
    erow_s[estartb[c] + atomicAdd(&ecursor[c], 1)] = erow[e];
  }
}

// ---------------- fused attention pass: gather x rows, score+exp inline, accumulate --------
// Block per region. Half-wave (32 lanes) per point, 4 points unrolled.
// Lane sl holds dims 4*sl..4*sl+3. After the 6-shuffle head-compaction reduce, each lane
// holds the score total for head (lane&3); 1 exp, then 3 shuffles distribute all 4 p's.
// Accumulators are head-RELATIVE: xagg[dd][hrel] belongs to head (lane&3)^hrel.
__global__ __launch_bounds__(256) void k_fused(
    const float* __restrict__ x, const int* __restrict__ perm, const int* __restrict__ startb,
    const float* __restrict__ A, const float* __restrict__ cvec,
    float* __restrict__ Xagg, float* __restrict__ denom) {
  const int r = blockIdx.x;
  const int s0 = startb[r], s1 = startb[r + 1];
  const int tid = threadIdx.x;
  const int lane = tid & 63;
  const int hw = tid >> 5;   // half-wave id 0..7
  const int sl = tid & 31;
  const int d0 = sl * 4;
  const int myh = lane & 3;

  float a[4][4];
#pragma unroll
  for (int dd = 0; dd < 4; ++dd)
#pragma unroll
    for (int h = 0; h < 4; ++h) a[dd][h] = A[(d0 + dd) * 4 + h];
  const float cl = cvec[myh];

  float xagg[4][4] = {};  // [dim][hrel]
  float dsum[4] = {};     // [hrel] -- NOTE: every lane accumulates ALL 4 heads

  for (int i = s0 + hw * 4; i < s1; i += 32) {
    float4 xv[4];
    bool val[4];
#pragma unroll
    for (int k = 0; k < 4; ++k) {
      const int j = i + k;
      val[k] = j < s1;
      const int idx = val[k] ? perm[j] : perm[s0];
      xv[k] = *reinterpret_cast<const float4*>(x + (size_t)idx * 128 + d0);
    }
    float s[4][4];
#pragma unroll
    for (int k = 0; k < 4; ++k)
#pragma unroll
      for (int h = 0; h < 4; ++h)
        s[k][h] = xv[k].x * a[0][h] + xv[k].y * a[1][h] + xv[k].z * a[2][h] + xv[k].w * a[3][h];
    float red[4];
#pragma unroll
    for (int k = 0; k < 4; ++k) {
      float a01 = (lane & 1) ? s[k][1] : s[k][0];
      float b01 = (lane & 1) ? s[k][0] : s[k][1];
      a01 += __shfl_xor(b01, 1, 64);
      float a23 = (lane & 1) ? s[k][3] : s[k][2];
      float b23 = (lane & 1) ? s[k][2] : s[k][3];
      a23 += __shfl_xor(b23, 1, 64);
      float aa = (lane & 2) ? a23 : a01;
      float bb = (lane & 2) ? a01 : a23;
      aa += __shfl_xor(bb, 2, 64);
      aa += __shfl_xor(aa, 4, 64);
      aa += __shfl_xor(aa, 8, 64);
      aa += __shfl_xor(aa, 16, 64);
      red[k] = aa;
    }
#pragma unroll
    for (int k = 0; k < 4; ++k) {
      const float e0 = val[k] ? __expf(red[k] + cl) : 0.f; // head myh
      const float e1 = __shfl_xor(e0, 1, 64);              // head myh^1
      const float e2 = __shfl_xor(e0, 2, 64);              // head myh^2
      const float e3 = __shfl_xor(e0, 3, 64);              // head myh^3
      dsum[0] += e0; dsum[1] += e1; dsum[2] += e2; dsum[3] += e3;
      const float4 v = xv[k];
      xagg[0][0] += e0 * v.x; xagg[0][1] += e1 * v.x; xagg[0][2] += e2 * v.x; xagg[0][3] += e3 * v.x;
      xagg[1][0] += e0 * v.y; xagg[1][1] += e1 * v.y; xagg[1][2] += e2 * v.y; xagg[1][3] += e3 * v.y;
      xagg[2][0] += e0 * v.z; xagg[2][1] += e1 * v.z; xagg[2][2] += e2 * v.z; xagg[2][3] += e3 * v.z;
      xagg[3][0] += e0 * v.w; xagg[3][1] += e1 * v.w; xagg[3][2] += e2 * v.w; xagg[3][3] += e3 * v.w;
    }
  }

  __shared__ float s_xagg[512]; // [dim][head] layout: dim*4+h
  __shared__ float s_den[4];
  for (int t = tid; t < 512; t += 256) s_xagg[t] = 0.f;
  if (tid < 4) s_den[tid] = 0.f;
  __syncthreads();
#pragma unroll
  for (int dd = 0; dd < 4; ++dd)
#pragma unroll
    for (int hrel = 0; hrel < 4; ++hrel)
      atomicAdd(&s_xagg[(d0 + dd) * 4 + (myh ^ hrel)], xagg[dd][hrel]);
  // Every lane holds the full per-half-wave dsum (all 4 heads). Flush from ONE lane
  // per half-wave only (sl==0 -> myh==0, so dsum[hrel] belongs to head hrel).
  if (sl == 0) {
#pragma unroll
    for (int hrel = 0; hrel < 4; ++hrel) atomicAdd(&s_den[hrel], dsum[hrel]);
  }
  __syncthreads();
  for (int t = tid; t < 512; t += 256) {
    int h = t >> 7, j = t & 127;
    Xagg[(size_t)r * 512 + t] = s_xagg[j * 4 + h];
  }
  if (tid < 4) denom[r * 4 + tid] = s_den[tid];
}

// ---------------- batched epilogue: attn -> O -> O+relu(O@Wo+bo) -> h = O2@Wg  (8 regions/block) --------
__global__ __launch_bounds__(256) void k_epilogue(
    const float* __restrict__ Xagg, const float* __restrict__ denom, const float* __restrict__ qvec,
    const float* __restrict__ Wv, const float* __restrict__ bv,
    const float* __restrict__ Wo, const float* __restrict__ bo,
    const float* __restrict__ Wg, float* __restrict__ hout, int R) {
  const int r0 = blockIdx.x * 8;
  const int tid = threadIdx.x;
  __shared__ float s_xa[8 * 512];
  __shared__ float s_den[8 * 4];
  __shared__ float s_O[8 * 128];
  __shared__ float s_O2[8 * 128];

  for (int t = tid; t < 8 * 512; t += 256) {
    int rl = t >> 9;
    s_xa[t] = (r0 + rl < R) ? Xagg[(size_t)r0 * 512 + t] : 0.f;
  }
  if (tid < 32) {
    int rl = tid >> 2;
    s_den[tid] = (r0 + rl < R) ? denom[r0 * 4 + tid] : 1.f;
  }
  __syncthreads();

  for (int o = tid; o < 1024; o += 256) {
    int rl = o >> 7, t = o & 127, h = t >> 5;
    float acc = 0.f;
    const float* xa = &s_xa[rl * 512 + h * 128];
    for (int j = 0; j < 128; j += 4) {
      float4 x4 = *reinterpret_cast<const float4*>(xa + j);
      acc += x4.x * Wv[j * 128 + t] + x4.y * Wv[(j + 1) * 128 + t]
           + x4.z * Wv[(j + 2) * 128 + t] + x4.w * Wv[(j + 3) * 128 + t];
    }
    float dn = s_den[rl * 4 + h];
    float attn = (acc + dn * bv[t]) / fmaxf(dn, 1e-9f);
    s_O[o] = qvec[t] + attn;
  }
  __syncthreads();

  for (int o = tid; o < 1024; o += 256) {
    int rl = o >> 7, t = o & 127;
    float acc = bo[t];
    const float* ov = &s_O[rl * 128];
    for (int j = 0; j < 128; j += 4) {
      float4 x4 = *reinterpret_cast<const float4*>(ov + j);
      acc += x4.x * Wo[j * 128 + t] + x4.y * Wo[(j + 1) * 128 + t]
           + x4.z * Wo[(j + 2) * 128 + t] + x4.w * Wo[(j + 3) * 128 + t];
    }
    s_O2[o] = s_O[o] + fmaxf(acc, 0.f);
  }
  __syncthreads();

  for (int o = tid; o < 1024; o += 256) {
    int rl = o >> 7, t = o & 127;
    float acc = 0.f;
    const float* ov = &s_O2[rl * 128];
    for (int j = 0; j < 128; j += 4) {
      float4 x4 = *reinterpret_cast<const float4*>(ov + j);
      acc += x4.x * Wg[j * 128 + t] + x4.y * Wg[(j + 1) * 128 + t]
           + x4.z * Wg[(j + 2) * 128 + t] + x4.w * Wg[(j + 3) * 128 + t];
    }
    if (r0 + rl < R) hout[(size_t)(r0 + rl) * 128 + t] = acc;
  }
}

// ---------------- fused GCN: self-loop + CSR edge gather + bias + PReLU (wave per region) ----------------
__global__ __launch_bounds__(256) void k_gcn(
    const int* __restrict__ estartb, const int* __restrict__ erow_s,
    const float* __restrict__ dinv, const float* __restrict__ hbuf,
    const float* __restrict__ bg, const float* __restrict__ pw,
    float* __restrict__ out, int R) {
  const int r = blockIdx.x * 4 + (threadIdx.x >> 6);
  if (r >= R) return;
  const int lane = threadIdx.x & 63;
  const int d0 = lane * 2;
  const float dr = dinv[r];
  const float2 hc = *reinterpret_cast<const float2*>(hbuf + (size_t)r * 128 + d0);
  float accx = dr * dr * hc.x;
  float accy = dr * dr * hc.y;
  const int e0 = estartb[r], e1 = estartb[r + 1];
  for (int e = e0; e < e1; ++e) {
    const int rr = erow_s[e];
    const float w = dinv[rr] * dr;
    const float2 hv = *reinterpret_cast<const float2*>(hbuf + (size_t)rr * 128 + d0);
    accx += w * hv.x;
    accy += w * hv.y;
  }
  const float2 b = *reinterpret_cast<const float2*>(bg + d0);
  const float2 pv = *reinterpret_cast<const float2*>(pw + d0);
  const float t0 = accx + b.x;
  const float t1 = accy + b.y;
  out[(size_t)r * 128 + d0]     = (t0 >= 0.f) ? t0 : pv.x * t0;
  out[(size_t)r * 128 + d0 + 1] = (t1 >= 0.f) ? t1 : pv.y * t1;
}

// ---------------- host ----------------
extern "C" void kernel_launch(void* const* d_in, const int* in_sizes, int n_in,
                              void* d_out, int out_size, void* d_ws, size_t ws_size,
                              hipStream_t stream) {
  const float* x   = (const float*)d_in[0];
  const int*   zone = (const int*)d_in[1];
  const int*   eidx = (const int*)d_in[2];
  const float* S   = (const float*)d_in[4];
  const float* Wq  = (const float*)d_in[5];
  const float* bq  = (const float*)d_in[6];
  const float* Wk  = (const float*)d_in[7];
  const float* bk  = (const float*)d_in[8];
  const float* Wv  = (const float*)d_in[9];
  const float* bv  = (const float*)d_in[10];
  const float* Wo  = (const float*)d_in[11];
  const float* bo  = (const float*)d_in[12];
  const float* Wg  = (const float*)d_in[13];
  const float* bg  = (const float*)d_in[14];
  const float* pw  = (const float*)d_in[15];
  float* out = (float*)d_out;

  const int N = in_sizes[0] / 128;
  const int E = in_sizes[2] / 2;
  const int R = out_size / 128;
  const int* erow = eidx;
  const int* ecol = eidx + E;

  char* wsb = (char*)d_ws;
  size_t off = 0;
  auto alloc = [&](size_t bytes) -> void* {
    void* p = wsb + off;
    off = (off + bytes + 255) & ~(size_t)255;
    return p;
  };
  // zeroed int block: counts | cursor | ecounts | ecursor
  int* izero  = (int*)alloc((size_t)4 * R * 4);
  int* counts = izero;
  int* cursor = izero + R;
  int* ecounts= izero + 2 * R;
  int* ecursor= izero + 3 * R;

  float* qvec  = (float*)alloc(128 * 4);
  float* A     = (float*)alloc(512 * 4);
  float* cvec  = (float*)alloc(4 * 4);
  int*   startb = (int*)alloc((size_t)(R + 1) * 4);
  int*   estartb= (int*)alloc((size_t)(R + 1) * 4);
  float* dinv  = (float*)alloc((size_t)R * 4);
  int*   erow_s= (int*)alloc((size_t)E * 4);
  int*   perm  = (int*)alloc((size_t)N * 4);
  float* Xagg  = (float*)alloc((size_t)R * 512 * 4);
  float* denom = (float*)alloc((size_t)R * 4 * 4);
  float* hbuf  = (float*)alloc((size_t)R * 128 * 4);

  const int n4 = R; // 4*R ints = R int4s
  k_zero<<<(n4 + 255) / 256, 256, 0, stream>>>(izero, n4);
  k_precompute<<<1, 128, 0, stream>>>(S, Wq, bq, Wk, bk, qvec, A, cvec);
  k_hist2<<<(N + E + 255) / 256, 256, 0, stream>>>(zone, N, ecol, E, counts, ecounts);
  k_scan2<<<2, 256, 0, stream>>>(counts, ecounts, R, startb, estartb, dinv);
  k_scatter2<<<(N + E + 255) / 256, 256, 0, stream>>>(zone, N, erow, ecol, E,
                                                      startb, cursor, perm, estartb, ecursor, erow_s);
  k_fused<<<R, 256, 0, stream>>>(x, perm, startb, A, cvec, Xagg, denom);
  k_epilogue<<<(R + 7) / 8, 256, 0, stream>>>(Xagg, denom, qvec, Wv, bv, Wo, bo, Wg, hbuf, R);
  k_gcn<<<(R + 3) / 4, 256, 0, stream>>>(estartb, erow_s, dinv, hbuf, bg, pw, out, R);
}

// Round 7
// 525.750 us; speedup vs baseline: 1.1115x; 1.0276x over previous
//
#include <hip/hip_runtime.h>
#include <math.h>

// ---------------- init: blocks [0,zb) zero the counter block; block zb does precompute ----------------
// precompute: qvec = S@Wq + bq; A[j][h] = (Wk[j,h*32:]·q_h)/sqrt(128); c[h] = bk_h·q_h/sqrt(128)
__global__ __launch_bounds__(256) void k_init(
    int* __restrict__ izero, int n4, int zb,
    const float* __restrict__ S, const float* __restrict__ Wq, const float* __restrict__ bq,
    const float* __restrict__ Wk, const float* __restrict__ bk,
    float* __restrict__ qvec, float* __restrict__ A, float* __restrict__ cvec) {
  if (blockIdx.x < (unsigned)zb) {
    int i = blockIdx.x * blockDim.x + threadIdx.x;
    if (i < n4) reinterpret_cast<int4*>(izero)[i] = make_int4(0, 0, 0, 0);
    return;
  }
  __shared__ float s_S[128];
  __shared__ float s_q[128];
  const int j = threadIdx.x;
  if (j < 128) s_S[j] = S[j];
  __syncthreads();
  float acc = 0.f;
  if (j < 128) {
    acc = bq[j];
    for (int i = 0; i < 128; ++i) acc += s_S[i] * Wq[i * 128 + j];
    qvec[j] = acc;
    s_q[j] = acc;
  }
  __syncthreads();
  if (j < 128) {
    const float scale = 0.088388347648318447f; // 1/sqrt(128)
    for (int h = 0; h < 4; ++h) {
      float a = 0.f;
      for (int d = 0; d < 32; ++d) a += Wk[j * 128 + h * 32 + d] * s_q[h * 32 + d];
      A[j * 4 + h] = a * scale;
    }
    if (j < 4) {
      float cc = 0.f;
      for (int d = 0; d < 32; ++d) cc += bk[j * 32 + d] * s_q[j * 32 + d];
      cvec[j] = cc * scale;
    }
  }
}

// ---------------- phase A: stream x coalesced, compute p (unsorted), zone hist, edge hist --------
// Blocks [0,NBP): half-wave per point, 2 points per iteration. Blocks [NBP, NBP+NBE): edge histogram.
__global__ __launch_bounds__(256) void k_A(
    const float* __restrict__ x, const int* __restrict__ zone,
    const float* __restrict__ A, const float* __restrict__ cvec,
    int* __restrict__ counts, float* __restrict__ p, int N, int NBP,
    const int* __restrict__ ecol, int E, int* __restrict__ ecounts, int NBE) {
  const int tid = threadIdx.x;
  if ((int)blockIdx.x >= NBP) {
    int t = (blockIdx.x - NBP) * 256 + tid;
    const int stride = NBE * 256;
    for (; t < E; t += stride) atomicAdd(&ecounts[ecol[t]], 1);
    return;
  }
  const int lane = tid & 63;
  const int hw = tid >> 5;      // half-wave id 0..7
  const int sl = tid & 31;
  const int d0 = sl * 4;
  float a[4][4];
#pragma unroll
  for (int dd = 0; dd < 4; ++dd)
#pragma unroll
    for (int h = 0; h < 4; ++h) a[dd][h] = A[(d0 + dd) * 4 + h];
  const float cl = cvec[lane & 3];

  const int stride = NBP * 16;
  for (int i0 = (blockIdx.x * 8 + hw) * 2; i0 < N; i0 += stride) {
    const int i1 = i0 + 1;
    const bool v1 = i1 < N;
    const float4 xv0 = *reinterpret_cast<const float4*>(x + (size_t)i0 * 128 + d0);
    float4 xv1 = make_float4(0.f, 0.f, 0.f, 0.f);
    if (v1) xv1 = *reinterpret_cast<const float4*>(x + (size_t)i1 * 128 + d0);
    float s0[4], s1[4];
#pragma unroll
    for (int h = 0; h < 4; ++h) {
      s0[h] = xv0.x * a[0][h] + xv0.y * a[1][h] + xv0.z * a[2][h] + xv0.w * a[3][h];
      s1[h] = xv1.x * a[0][h] + xv1.y * a[1][h] + xv1.z * a[2][h] + xv1.w * a[3][h];
    }
    float red[2];
    {
      float a01 = (lane & 1) ? s0[1] : s0[0];
      float b01 = (lane & 1) ? s0[0] : s0[1];
      a01 += __shfl_xor(b01, 1, 64);
      float a23 = (lane & 1) ? s0[3] : s0[2];
      float b23 = (lane & 1) ? s0[2] : s0[3];
      a23 += __shfl_xor(b23, 1, 64);
      float aa = (lane & 2) ? a23 : a01;
      float bb = (lane & 2) ? a01 : a23;
      aa += __shfl_xor(bb, 2, 64);
      aa += __shfl_xor(aa, 4, 64);
      aa += __shfl_xor(aa, 8, 64);
      aa += __shfl_xor(aa, 16, 64);
      red[0] = aa;
    }
    {
      float a01 = (lane & 1) ? s1[1] : s1[0];
      float b01 = (lane & 1) ? s1[0] : s1[1];
      a01 += __shfl_xor(b01, 1, 64);
      float a23 = (lane & 1) ? s1[3] : s1[2];
      float b23 = (lane & 1) ? s1[2] : s1[3];
      a23 += __shfl_xor(b23, 1, 64);
      float aa = (lane & 2) ? a23 : a01;
      float bb = (lane & 2) ? a01 : a23;
      aa += __shfl_xor(bb, 2, 64);
      aa += __shfl_xor(aa, 4, 64);
      aa += __shfl_xor(aa, 8, 64);
      aa += __shfl_xor(aa, 16, 64);
      red[1] = aa;
    }
    const float e0 = __expf(red[0] + cl);
    const float e1 = __expf(red[1] + cl);
    if (sl < 4) {
      p[(size_t)i0 * 4 + sl] = e0;           // lane sl holds head sl
      if (v1) p[(size_t)i1 * 4 + sl] = e1;
    }
    if (sl == 0) {
      atomicAdd(&counts[zone[i0]], 1);
      if (v1) atomicAdd(&counts[zone[i1]], 1);
    }
  }
}

// ---------------- combined scan: block 0 scans point counts; block 1 scans edge counts + dinv --------
__global__ __launch_bounds__(256) void k_scan2(const int* __restrict__ counts, const int* __restrict__ ecounts,
                                               int R, int* __restrict__ startb, int* __restrict__ estartb,
                                               float* __restrict__ dinv) {
  __shared__ int part[256];
  const int t = threadIdx.x;
  const bool edges = (blockIdx.x == 1);
  const int* __restrict__ cnt = edges ? ecounts : counts;
  int* __restrict__ outp = edges ? estartb : startb;
  int chunk = (R + 255) / 256;
  int b = t * chunk, e = min(b + chunk, R);
  int s = 0;
  for (int i = b; i < e; ++i) s += cnt[i];
  part[t] = s;
  __syncthreads();
  for (int off = 1; off < 256; off <<= 1) {
    int v = (t >= off) ? part[t - off] : 0;
    __syncthreads();
    part[t] += v;
    __syncthreads();
  }
  int run = part[t] - s; // exclusive prefix
  for (int i = b; i < e; ++i) {
    outp[i] = run;
    int c = cnt[i];
    run += c;
    if (edges) dinv[i] = rsqrtf((float)(c + 1)); // +1 self loop
  }
  if (t == 255) outp[R] = part[255];
}

// ---------------- merged scatter: point indices + p4 by zone; edge rows by col ----------------
__global__ __launch_bounds__(256) void k_scatter2(
    const int* __restrict__ zone, int N, const float* __restrict__ p,
    const int* __restrict__ erow, const int* __restrict__ ecol, int E,
    const int* __restrict__ startb, int* __restrict__ cursor, int* __restrict__ perm,
    float* __restrict__ p_sorted,
    const int* __restrict__ estartb, int* __restrict__ ecursor, int* __restrict__ erow_s) {
  int i = blockIdx.x * blockDim.x + threadIdx.x;
  if (i < N) {
    int r = zone[i];
    int pos = startb[r] + atomicAdd(&cursor[r], 1);
    perm[pos] = i;
    const float4 q = *reinterpret_cast<const float4*>(p + (size_t)i * 4);
    reinterpret_cast<float4*>(p_sorted)[pos] = q;
  } else if (i < N + E) {
    int e = i - N;
    int c = ecol[e];
    erow_s[estartb[c] + atomicAdd(&ecursor[c], 1)] = erow[e];
  }
}

// ---------------- phase B: per-region gather + weighted accumulate (no shuffles, no exp) --------
// Block per region, half-wave per point, 8 points in flight. Lane sl owns dims 4*sl..4*sl+3.
__global__ __launch_bounds__(256) void k_B(
    const float* __restrict__ x, const int* __restrict__ perm, const int* __restrict__ startb,
    const float* __restrict__ p_sorted,
    float* __restrict__ Xagg, float* __restrict__ denom) {
  const int r = blockIdx.x;
  const int s0 = startb[r], s1 = startb[r + 1];
  const int tid = threadIdx.x;
  const int hw = tid >> 5;
  const int sl = tid & 31;
  const int d0 = sl * 4;

  float xagg[4][4] = {};  // [dim][head], absolute heads
  float dsum[4] = {};

  for (int base = s0 + hw * 8; base < s1; base += 64) {
    float4 xv[8], qq[8];
#pragma unroll
    for (int k = 0; k < 8; ++k) {
      const int j = base + k;
      if (j < s1) {
        const int idx = perm[j];
        xv[k] = *reinterpret_cast<const float4*>(x + (size_t)idx * 128 + d0);
        qq[k] = reinterpret_cast<const float4*>(p_sorted)[j];
      } else {
        xv[k] = make_float4(0.f, 0.f, 0.f, 0.f);
        qq[k] = make_float4(0.f, 0.f, 0.f, 0.f);
      }
    }
#pragma unroll
    for (int k = 0; k < 8; ++k) {
      const float4 q = qq[k];
      const float4 v = xv[k];
      xagg[0][0] += q.x * v.x; xagg[0][1] += q.y * v.x; xagg[0][2] += q.z * v.x; xagg[0][3] += q.w * v.x;
      xagg[1][0] += q.x * v.y; xagg[1][1] += q.y * v.y; xagg[1][2] += q.z * v.y; xagg[1][3] += q.w * v.y;
      xagg[2][0] += q.x * v.z; xagg[2][1] += q.y * v.z; xagg[2][2] += q.z * v.z; xagg[2][3] += q.w * v.z;
      xagg[3][0] += q.x * v.w; xagg[3][1] += q.y * v.w; xagg[3][2] += q.z * v.w; xagg[3][3] += q.w * v.w;
      dsum[0] += q.x; dsum[1] += q.y; dsum[2] += q.z; dsum[3] += q.w;
    }
  }

  __shared__ float s_xagg[512]; // [dim][head] layout: dim*4+h
  __shared__ float s_den[4];
  for (int t = tid; t < 512; t += 256) s_xagg[t] = 0.f;
  if (tid < 4) s_den[tid] = 0.f;
  __syncthreads();
#pragma unroll
  for (int dd = 0; dd < 4; ++dd)
#pragma unroll
    for (int h = 0; h < 4; ++h) atomicAdd(&s_xagg[(d0 + dd) * 4 + h], xagg[dd][h]);
  // all lanes of a half-wave hold identical dsum -> flush once per half-wave
  if (sl == 0) {
#pragma unroll
    for (int h = 0; h < 4; ++h) atomicAdd(&s_den[h], dsum[h]);
  }
  __syncthreads();
  for (int t = tid; t < 512; t += 256) {
    int h = t >> 7, j = t & 127;
    Xagg[(size_t)r * 512 + t] = s_xagg[j * 4 + h];
  }
  if (tid < 4) denom[r * 4 + tid] = s_den[tid];
}

// ---------------- batched epilogue: attn -> O -> O+relu(O@Wo+bo) -> h = O2@Wg  (8 regions/block) --------
__global__ __launch_bounds__(256) void k_epilogue(
    const float* __restrict__ Xagg, const float* __restrict__ denom, const float* __restrict__ qvec,
    const float* __restrict__ Wv, const float* __restrict__ bv,
    const float* __restrict__ Wo, const float* __restrict__ bo,
    const float* __restrict__ Wg, float* __restrict__ hout, int R) {
  const int r0 = blockIdx.x * 8;
  const int tid = threadIdx.x;
  __shared__ float s_xa[8 * 512];
  __shared__ float s_den[8 * 4];
  __shared__ float s_O[8 * 128];
  __shared__ float s_O2[8 * 128];

  for (int t = tid; t < 8 * 512; t += 256) {
    int rl = t >> 9;
    s_xa[t] = (r0 + rl < R) ? Xagg[(size_t)r0 * 512 + t] : 0.f;
  }
  if (tid < 32) {
    int rl = tid >> 2;
    s_den[tid] = (r0 + rl < R) ? denom[r0 * 4 + tid] : 1.f;
  }
  __syncthreads();

  for (int o = tid; o < 1024; o += 256) {
    int rl = o >> 7, t = o & 127, h = t >> 5;
    float acc = 0.f;
    const float* xa = &s_xa[rl * 512 + h * 128];
    for (int j = 0; j < 128; j += 4) {
      float4 x4 = *reinterpret_cast<const float4*>(xa + j);
      acc += x4.x * Wv[j * 128 + t] + x4.y * Wv[(j + 1) * 128 + t]
           + x4.z * Wv[(j + 2) * 128 + t] + x4.w * Wv[(j + 3) * 128 + t];
    }
    float dn = s_den[rl * 4 + h];
    float attn = (acc + dn * bv[t]) / fmaxf(dn, 1e-9f);
    s_O[o] = qvec[t] + attn;
  }
  __syncthreads();

  for (int o = tid; o < 1024; o += 256) {
    int rl = o >> 7, t = o & 127;
    float acc = bo[t];
    const float* ov = &s_O[rl * 128];
    for (int j = 0; j < 128; j += 4) {
      float4 x4 = *reinterpret_cast<const float4*>(ov + j);
      acc += x4.x * Wo[j * 128 + t] + x4.y * Wo[(j + 1) * 128 + t]
           + x4.z * Wo[(j + 2) * 128 + t] + x4.w * Wo[(j + 3) * 128 + t];
    }
    s_O2[o] = s_O[o] + fmaxf(acc, 0.f);
  }
  __syncthreads();

  for (int o = tid; o < 1024; o += 256) {
    int rl = o >> 7, t = o & 127;
    float acc = 0.f;
    const float* ov = &s_O2[rl * 128];
    for (int j = 0; j < 128; j += 4) {
      float4 x4 = *reinterpret_cast<const float4*>(ov + j);
      acc += x4.x * Wg[j * 128 + t] + x4.y * Wg[(j + 1) * 128 + t]
           + x4.z * Wg[(j + 2) * 128 + t] + x4.w * Wg[(j + 3) * 128 + t];
    }
    if (r0 + rl < R) hout[(size_t)(r0 + rl) * 128 + t] = acc;
  }
}

// ---------------- fused GCN: self-loop + CSR edge gather + bias + PReLU (wave per region) ----------------
__global__ __launch_bounds__(256) void k_gcn(
    const int* __restrict__ estartb, const int* __restrict__ erow_s,
    const float* __restrict__ dinv, const float* __restrict__ hbuf,
    const float* __restrict__ bg, const float* __restrict__ pw,
    float* __restrict__ out, int R) {
  const int r = blockIdx.x * 4 + (threadIdx.x >> 6);
  if (r >= R) return;
  const int lane = threadIdx.x & 63;
  const int d0 = lane * 2;
  const float dr = dinv[r];
  const float2 hc = *reinterpret_cast<const float2*>(hbuf + (size_t)r * 128 + d0);
  float accx = dr * dr * hc.x;
  float accy = dr * dr * hc.y;
  const int e0 = estartb[r], e1 = estartb[r + 1];
  for (int e = e0; e < e1; ++e) {
    const int rr = erow_s[e];
    const float w = dinv[rr] * dr;
    const float2 hv = *reinterpret_cast<const float2*>(hbuf + (size_t)rr * 128 + d0);
    accx += w * hv.x;
    accy += w * hv.y;
  }
  const float2 b = *reinterpret_cast<const float2*>(bg + d0);
  const float2 pv = *reinterpret_cast<const float2*>(pw + d0);
  const float t0 = accx + b.x;
  const float t1 = accy + b.y;
  out[(size_t)r * 128 + d0]     = (t0 >= 0.f) ? t0 : pv.x * t0;
  out[(size_t)r * 128 + d0 + 1] = (t1 >= 0.f) ? t1 : pv.y * t1;
}

// ---------------- host ----------------
extern "C" void kernel_launch(void* const* d_in, const int* in_sizes, int n_in,
                              void* d_out, int out_size, void* d_ws, size_t ws_size,
                              hipStream_t stream) {
  const float* x   = (const float*)d_in[0];
  const int*   zone = (const int*)d_in[1];
  const int*   eidx = (const int*)d_in[2];
  const float* S   = (const float*)d_in[4];
  const float* Wq  = (const float*)d_in[5];
  const float* bq  = (const float*)d_in[6];
  const float* Wk  = (const float*)d_in[7];
  const float* bk  = (const float*)d_in[8];
  const float* Wv  = (const float*)d_in[9];
  const float* bv  = (const float*)d_in[10];
  const float* Wo  = (const float*)d_in[11];
  const float* bo  = (const float*)d_in[12];
  const float* Wg  = (const float*)d_in[13];
  const float* bg  = (const float*)d_in[14];
  const float* pw  = (const float*)d_in[15];
  float* out = (float*)d_out;

  const int N = in_sizes[0] / 128;
  const int E = in_sizes[2] / 2;
  const int R = out_size / 128;
  const int* erow = eidx;
  const int* ecol = eidx + E;

  char* wsb = (char*)d_ws;
  size_t off = 0;
  auto alloc = [&](size_t bytes) -> void* {
    void* p = wsb + off;
    off = (off + bytes + 255) & ~(size_t)255;
    return p;
  };
  // zeroed int block: counts | cursor | ecounts | ecursor
  int* izero  = (int*)alloc((size_t)4 * R * 4);
  int* counts = izero;
  int* cursor = izero + R;
  int* ecounts= izero + 2 * R;
  int* ecursor= izero + 3 * R;

  float* qvec  = (float*)alloc(128 * 4);
  float* A     = (float*)alloc(512 * 4);
  float* cvec  = (float*)alloc(4 * 4);
  int*   startb = (int*)alloc((size_t)(R + 1) * 4);
  int*   estartb= (int*)alloc((size_t)(R + 1) * 4);
  float* dinv  = (float*)alloc((size_t)R * 4);
  int*   erow_s= (int*)alloc((size_t)E * 4);
  int*   perm  = (int*)alloc((size_t)N * 4);
  float* p_uns = (float*)alloc((size_t)N * 4 * 4);
  float* p_srt = (float*)alloc((size_t)N * 4 * 4);
  float* Xagg  = (float*)alloc((size_t)R * 512 * 4);
  float* denom = (float*)alloc((size_t)R * 4 * 4);
  float* hbuf  = (float*)alloc((size_t)R * 128 * 4);

  const int n4 = R; // 4*R ints = R int4s
  const int zb = (n4 + 255) / 256;
  k_init<<<zb + 1, 256, 0, stream>>>(izero, n4, zb, S, Wq, bq, Wk, bk, qvec, A, cvec);
  const int NBP = 4096, NBE = 64;
  k_A<<<NBP + NBE, 256, 0, stream>>>(x, zone, A, cvec, counts, p_uns, N, NBP, ecol, E, ecounts, NBE);
  k_scan2<<<2, 256, 0, stream>>>(counts, ecounts, R, startb, estartb, dinv);
  k_scatter2<<<(N + E + 255) / 256, 256, 0, stream>>>(zone, N, p_uns, erow, ecol, E,
                                                      startb, cursor, perm, p_srt,
                                                      estartb, ecursor, erow_s);
  k_B<<<R, 256, 0, stream>>>(x, perm, startb, p_srt, Xagg, denom);
  k_epilogue<<<(R + 7) / 8, 256, 0, stream>>>(Xagg, denom, qvec, Wv, bv, Wo, bo, Wg, hbuf, R);
  k_gcn<<<(R + 3) / 4, 256, 0, stream>>>(estartb, erow_s, dinv, hbuf, bg, pw, out, R);
}

// Round 8
// 371.373 us; speedup vs baseline: 1.5736x; 1.4157x over previous
//
#include <hip/hip_runtime.h>
#include <math.h>

// ---------------- init: blocks [0,zb) zero the counter block; block zb does precompute ----------------
__global__ __launch_bounds__(256) void k_init(
    int* __restrict__ izero, int n4, int zb,
    const float* __restrict__ S, const float* __restrict__ Wq, const float* __restrict__ bq,
    const float* __restrict__ Wk, const float* __restrict__ bk,
    float* __restrict__ qvec, float* __restrict__ A, float* __restrict__ cvec) {
  if (blockIdx.x < (unsigned)zb) {
    int i = blockIdx.x * blockDim.x + threadIdx.x;
    if (i < n4) reinterpret_cast<int4*>(izero)[i] = make_int4(0, 0, 0, 0);
    return;
  }
  __shared__ float s_S[128];
  __shared__ float s_q[128];
  const int j = threadIdx.x;
  if (j < 128) s_S[j] = S[j];
  __syncthreads();
  if (j < 128) {
    float acc = bq[j];
    for (int i = 0; i < 128; ++i) acc += s_S[i] * Wq[i * 128 + j];
    qvec[j] = acc;
    s_q[j] = acc;
  }
  __syncthreads();
  if (j < 128) {
    const float scale = 0.088388347648318447f; // 1/sqrt(128)
    for (int h = 0; h < 4; ++h) {
      float a = 0.f;
      for (int d = 0; d < 32; ++d) a += Wk[j * 128 + h * 32 + d] * s_q[h * 32 + d];
      A[j * 4 + h] = a * scale;
    }
    if (j < 4) {
      float cc = 0.f;
      for (int d = 0; d < 32; ++d) cc += bk[j * 32 + d] * s_q[j * 32 + d];
      cvec[j] = cc * scale;
    }
  }
}

// ---------------- combined histogram: zone counts (points) + col counts (edges) ----------------
__global__ __launch_bounds__(256) void k_hist2(const int* __restrict__ zone, int N,
                                               const int* __restrict__ ecol, int E,
                                               int* __restrict__ counts, int* __restrict__ ecounts) {
  int i = blockIdx.x * blockDim.x + threadIdx.x;
  if (i < N) {
    atomicAdd(&counts[zone[i]], 1);
  } else if (i < N + E) {
    atomicAdd(&ecounts[ecol[i - N]], 1);
  }
}

// ---------------- combined scan: block 0 scans point counts; block 1 scans edge counts + dinv --------
__global__ __launch_bounds__(256) void k_scan2(const int* __restrict__ counts, const int* __restrict__ ecounts,
                                               int R, int* __restrict__ startb, int* __restrict__ estartb,
                                               float* __restrict__ dinv) {
  __shared__ int part[256];
  const int t = threadIdx.x;
  const bool edges = (blockIdx.x == 1);
  const int* __restrict__ cnt = edges ? ecounts : counts;
  int* __restrict__ outp = edges ? estartb : startb;
  int chunk = (R + 255) / 256;
  int b = t * chunk, e = min(b + chunk, R);
  int s = 0;
  for (int i = b; i < e; ++i) s += cnt[i];
  part[t] = s;
  __syncthreads();
  for (int off = 1; off < 256; off <<= 1) {
    int v = (t >= off) ? part[t - off] : 0;
    __syncthreads();
    part[t] += v;
    __syncthreads();
  }
  int run = part[t] - s; // exclusive prefix
  for (int i = b; i < e; ++i) {
    outp[i] = run;
    int c = cnt[i];
    run += c;
    if (edges) dinv[i] = rsqrtf((float)(c + 1)); // +1 self loop
  }
  if (t == 255) outp[R] = part[255];
}

// ---------------- merged scatter: point indices by zone, edge rows by col ----------------
__global__ __launch_bounds__(256) void k_scatter2(
    const int* __restrict__ zone, int N,
    const int* __restrict__ erow, const int* __restrict__ ecol, int E,
    const int* __restrict__ startb, int* __restrict__ cursor, int* __restrict__ perm,
    const int* __restrict__ estartb, int* __restrict__ ecursor, int* __restrict__ erow_s) {
  int i = blockIdx.x * blockDim.x + threadIdx.x;
  if (i < N) {
    int r = zone[i];
    perm[startb[r] + atomicAdd(&cursor[r], 1)] = i;
  } else if (i < N + E) {
    int e = i - N;
    int c = ecol[e];
    erow_s[estartb[c] + atomicAdd(&ecursor[c], 1)] = erow[e];
  }
}

// ---------------- fused attention pass: wave per region (grid-stride), 8-pt batches/half-wave --------
// Lane sl owns dims 4*sl..4*sl+3. 6-shuffle head-compaction reduce leaves lane with the
// score for head (lane&3); 1 exp + 3 distribute shuffles. Accumulators head-RELATIVE:
// xagg[dd][hrel] = head (myh^hrel). Flush: xor-32 shuffle reduce + static reorder + float4 stores.
__global__ __launch_bounds__(256) void k_fused(
    const float* __restrict__ x, const int* __restrict__ perm, const int* __restrict__ startb,
    const float* __restrict__ Aw, const float* __restrict__ cvec,
    float* __restrict__ Xagg, float* __restrict__ denom, int R) {
  const int tid = threadIdx.x;
  const int lane = tid & 63;
  const int half = lane >> 5;
  const int sl = lane & 31;
  const int d0 = sl * 4;
  const int myh = lane & 3;
  const int gw = blockIdx.x * 4 + (tid >> 6);
  const int nw = gridDim.x * 4;

  float a[4][4];
#pragma unroll
  for (int dd = 0; dd < 4; ++dd)
#pragma unroll
    for (int h = 0; h < 4; ++h) a[dd][h] = Aw[(d0 + dd) * 4 + h];
  const float cl = cvec[myh];

  for (int r = gw; r < R; r += nw) {
    const int s0 = startb[r], s1 = startb[r + 1];
    float xagg[4][4] = {};  // [dim][hrel]
    float dsum[4] = {};     // [hrel]

    int base = s0 + half * 8;
    int idx[8];
#pragma unroll
    for (int k = 0; k < 8; ++k) {
      const int j = base + k;
      idx[k] = (j < s1) ? perm[j] : -1;
    }
    for (; base < s1; base += 16) {
      float4 xv[8];
#pragma unroll
      for (int k = 0; k < 8; ++k) {
        xv[k] = (idx[k] >= 0)
              ? *reinterpret_cast<const float4*>(x + (size_t)idx[k] * 128 + d0)
              : make_float4(0.f, 0.f, 0.f, 0.f);
      }
      // prefetch next batch's indices (off the critical path)
      int idxn[8];
      const int nb = base + 16;
#pragma unroll
      for (int k = 0; k < 8; ++k) {
        const int j = nb + k;
        idxn[k] = (j < s1) ? perm[j] : -1;
      }
      float red[8];
#pragma unroll
      for (int k = 0; k < 8; ++k) {
        const float4 v = xv[k];
        const float p0 = v.x * a[0][0] + v.y * a[1][0] + v.z * a[2][0] + v.w * a[3][0];
        const float p1 = v.x * a[0][1] + v.y * a[1][1] + v.z * a[2][1] + v.w * a[3][1];
        const float p2 = v.x * a[0][2] + v.y * a[1][2] + v.z * a[2][2] + v.w * a[3][2];
        const float p3 = v.x * a[0][3] + v.y * a[1][3] + v.z * a[2][3] + v.w * a[3][3];
        float a01 = (lane & 1) ? p1 : p0;
        float b01 = (lane & 1) ? p0 : p1;
        a01 += __shfl_xor(b01, 1, 64);
        float a23 = (lane & 1) ? p3 : p2;
        float b23 = (lane & 1) ? p2 : p3;
        a23 += __shfl_xor(b23, 1, 64);
        float aa = (lane & 2) ? a23 : a01;
        float bb = (lane & 2) ? a01 : a23;
        aa += __shfl_xor(bb, 2, 64);
        aa += __shfl_xor(aa, 4, 64);
        aa += __shfl_xor(aa, 8, 64);
        aa += __shfl_xor(aa, 16, 64);
        red[k] = aa;
      }
#pragma unroll
      for (int k = 0; k < 8; ++k) {
        const float e0 = (idx[k] >= 0) ? __expf(red[k] + cl) : 0.f; // head myh
        const float e1 = __shfl_xor(e0, 1, 64);                     // head myh^1
        const float e2 = __shfl_xor(e0, 2, 64);                     // head myh^2
        const float e3 = __shfl_xor(e0, 3, 64);                     // head myh^3
        dsum[0] += e0; dsum[1] += e1; dsum[2] += e2; dsum[3] += e3;
        const float4 v = xv[k];
        xagg[0][0] += e0 * v.x; xagg[0][1] += e1 * v.x; xagg[0][2] += e2 * v.x; xagg[0][3] += e3 * v.x;
        xagg[1][0] += e0 * v.y; xagg[1][1] += e1 * v.y; xagg[1][2] += e2 * v.y; xagg[1][3] += e3 * v.y;
        xagg[2][0] += e0 * v.z; xagg[2][1] += e1 * v.z; xagg[2][2] += e2 * v.z; xagg[2][3] += e3 * v.z;
        xagg[3][0] += e0 * v.w; xagg[3][1] += e1 * v.w; xagg[3][2] += e2 * v.w; xagg[3][3] += e3 * v.w;
      }
#pragma unroll
      for (int k = 0; k < 8; ++k) idx[k] = idxn[k];
    }

    // reduce the two half-waves (lane l and l^32 have same myh -> same hrel semantics)
#pragma unroll
    for (int dd = 0; dd < 4; ++dd)
#pragma unroll
      for (int h = 0; h < 4; ++h) xagg[dd][h] += __shfl_xor(xagg[dd][h], 32, 64);
#pragma unroll
    for (int h = 0; h < 4; ++h) dsum[h] += __shfl_xor(dsum[h], 32, 64);

    if (half == 0) {
      // relative -> absolute heads: abs[h] = rel[h ^ myh], static-indexed via 2 select stages
      const bool m1 = (myh & 1) != 0;
      const bool m2 = (myh & 2) != 0;
      float outv[4][4]; // [abs head][dim]
#pragma unroll
      for (int dd = 0; dd < 4; ++dd) {
        const float b0 = m1 ? xagg[dd][1] : xagg[dd][0];
        const float b1 = m1 ? xagg[dd][0] : xagg[dd][1];
        const float b2 = m1 ? xagg[dd][3] : xagg[dd][2];
        const float b3 = m1 ? xagg[dd][2] : xagg[dd][3];
        outv[0][dd] = m2 ? b2 : b0;
        outv[1][dd] = m2 ? b3 : b1;
        outv[2][dd] = m2 ? b0 : b2;
        outv[3][dd] = m2 ? b1 : b3;
      }
#pragma unroll
      for (int h = 0; h < 4; ++h) {
        const float4 v = make_float4(outv[h][0], outv[h][1], outv[h][2], outv[h][3]);
        *reinterpret_cast<float4*>(Xagg + (size_t)r * 512 + h * 128 + d0) = v;
      }
      if (sl == 0) { // myh==0 -> dsum already absolute
        *reinterpret_cast<float4*>(denom + (size_t)r * 4) =
            make_float4(dsum[0], dsum[1], dsum[2], dsum[3]);
      }
    }
  }
}

// ---------------- batched epilogue: attn -> O -> O+relu(O@Wo+bo) -> h = O2@Wg  (8 regions/block) --------
__global__ __launch_bounds__(256) void k_epilogue(
    const float* __restrict__ Xagg, const float* __restrict__ denom, const float* __restrict__ qvec,
    const float* __restrict__ Wv, const float* __restrict__ bv,
    const float* __restrict__ Wo, const float* __restrict__ bo,
    const float* __restrict__ Wg, float* __restrict__ hout, int R) {
  const int r0 = blockIdx.x * 8;
  const int tid = threadIdx.x;
  __shared__ float s_xa[8 * 512];
  __shared__ float s_den[8 * 4];
  __shared__ float s_O[8 * 128];
  __shared__ float s_O2[8 * 128];

  for (int t = tid; t < 8 * 512; t += 256) {
    int rl = t >> 9;
    s_xa[t] = (r0 + rl < R) ? Xagg[(size_t)r0 * 512 + t] : 0.f;
  }
  if (tid < 32) {
    int rl = tid >> 2;
    s_den[tid] = (r0 + rl < R) ? denom[r0 * 4 + tid] : 1.f;
  }
  __syncthreads();

  for (int o = tid; o < 1024; o += 256) {
    int rl = o >> 7, t = o & 127, h = t >> 5;
    float acc = 0.f;
    const float* xa = &s_xa[rl * 512 + h * 128];
    for (int j = 0; j < 128; j += 4) {
      float4 x4 = *reinterpret_cast<const float4*>(xa + j);
      acc += x4.x * Wv[j * 128 + t] + x4.y * Wv[(j + 1) * 128 + t]
           + x4.z * Wv[(j + 2) * 128 + t] + x4.w * Wv[(j + 3) * 128 + t];
    }
    float dn = s_den[rl * 4 + h];
    float attn = (acc + dn * bv[t]) / fmaxf(dn, 1e-9f);
    s_O[o] = qvec[t] + attn;
  }
  __syncthreads();

  for (int o = tid; o < 1024; o += 256) {
    int rl = o >> 7, t = o & 127;
    float acc = bo[t];
    const float* ov = &s_O[rl * 128];
    for (int j = 0; j < 128; j += 4) {
      float4 x4 = *reinterpret_cast<const float4*>(ov + j);
      acc += x4.x * Wo[j * 128 + t] + x4.y * Wo[(j + 1) * 128 + t]
           + x4.z * Wo[(j + 2) * 128 + t] + x4.w * Wo[(j + 3) * 128 + t];
    }
    s_O2[o] = s_O[o] + fmaxf(acc, 0.f);
  }
  __syncthreads();

  for (int o = tid; o < 1024; o += 256) {
    int rl = o >> 7, t = o & 127;
    float acc = 0.f;
    const float* ov = &s_O2[rl * 128];
    for (int j = 0; j < 128; j += 4) {
      float4 x4 = *reinterpret_cast<const float4*>(ov + j);
      acc += x4.x * Wg[j * 128 + t] + x4.y * Wg[(j + 1) * 128 + t]
           + x4.z * Wg[(j + 2) * 128 + t] + x4.w * Wg[(j + 3) * 128 + t];
    }
    if (r0 + rl < R) hout[(size_t)(r0 + rl) * 128 + t] = acc;
  }
}

// ---------------- fused GCN: self-loop + CSR edge gather + bias + PReLU (wave per region) ----------------
__global__ __launch_bounds__(256) void k_gcn(
    const int* __restrict__ estartb, const int* __restrict__ erow_s,
    const float* __restrict__ dinv, const float* __restrict__ hbuf,
    const float* __restrict__ bg, const float* __restrict__ pw,
    float* __restrict__ out, int R) {
  const int r = blockIdx.x * 4 + (threadIdx.x >> 6);
  if (r >= R) return;
  const int lane = threadIdx.x & 63;
  const int d0 = lane * 2;
  const float dr = dinv[r];
  const float2 hc = *reinterpret_cast<const float2*>(hbuf + (size_t)r * 128 + d0);
  float accx = dr * dr * hc.x;
  float accy = dr * dr * hc.y;
  const int e0 = estartb[r], e1 = estartb[r + 1];
  for (int e = e0; e < e1; ++e) {
    const int rr = erow_s[e];
    const float w = dinv[rr] * dr;
    const float2 hv = *reinterpret_cast<const float2*>(hbuf + (size_t)rr * 128 + d0);
    accx += w * hv.x;
    accy += w * hv.y;
  }
  const float2 b = *reinterpret_cast<const float2*>(bg + d0);
  const float2 pv = *reinterpret_cast<const float2*>(pw + d0);
  const float t0 = accx + b.x;
  const float t1 = accy + b.y;
  out[(size_t)r * 128 + d0]     = (t0 >= 0.f) ? t0 : pv.x * t0;
  out[(size_t)r * 128 + d0 + 1] = (t1 >= 0.f) ? t1 : pv.y * t1;
}

// ---------------- host ----------------
extern "C" void kernel_launch(void* const* d_in, const int* in_sizes, int n_in,
                              void* d_out, int out_size, void* d_ws, size_t ws_size,
                              hipStream_t stream) {
  const float* x   = (const float*)d_in[0];
  const int*   zone = (const int*)d_in[1];
  const int*   eidx = (const int*)d_in[2];
  const float* S   = (const float*)d_in[4];
  const float* Wq  = (const float*)d_in[5];
  const float* bq  = (const float*)d_in[6];
  const float* Wk  = (const float*)d_in[7];
  const float* bk  = (const float*)d_in[8];
  const float* Wv  = (const float*)d_in[9];
  const float* bv  = (const float*)d_in[10];
  const float* Wo  = (const float*)d_in[11];
  const float* bo  = (const float*)d_in[12];
  const float* Wg  = (const float*)d_in[13];
  const float* bg  = (const float*)d_in[14];
  const float* pw  = (const float*)d_in[15];
  float* out = (float*)d_out;

  const int N = in_sizes[0] / 128;
  const int E = in_sizes[2] / 2;
  const int R = out_size / 128;
  const int* erow = eidx;
  const int* ecol = eidx + E;

  char* wsb = (char*)d_ws;
  size_t off = 0;
  auto alloc = [&](size_t bytes) -> void* {
    void* p = wsb + off;
    off = (off + bytes + 255) & ~(size_t)255;
    return p;
  };
  // zeroed int block: counts | cursor | ecounts | ecursor
  int* izero  = (int*)alloc((size_t)4 * R * 4);
  int* counts = izero;
  int* cursor = izero + R;
  int* ecounts= izero + 2 * R;
  int* ecursor= izero + 3 * R;

  float* qvec  = (float*)alloc(128 * 4);
  float* A     = (float*)alloc(512 * 4);
  float* cvec  = (float*)alloc(4 * 4);
  int*   startb = (int*)alloc((size_t)(R + 1) * 4);
  int*   estartb= (int*)alloc((size_t)(R + 1) * 4);
  float* dinv  = (float*)alloc((size_t)R * 4);
  int*   erow_s= (int*)alloc((size_t)E * 4);
  int*   perm  = (int*)alloc((size_t)N * 4);
  float* Xagg  = (float*)alloc((size_t)R * 512 * 4);
  float* denom = (float*)alloc((size_t)R * 4 * 4);
  float* hbuf  = (float*)alloc((size_t)R * 128 * 4);

  const int n4 = R; // 4*R ints = R int4s
  const int zb = (n4 + 255) / 256;
  k_init<<<zb + 1, 256, 0, stream>>>(izero, n4, zb, S, Wq, bq, Wk, bk, qvec, A, cvec);
  k_hist2<<<(N + E + 255) / 256, 256, 0, stream>>>(zone, N, ecol, E, counts, ecounts);
  k_scan2<<<2, 256, 0, stream>>>(counts, ecounts, R, startb, estartb, dinv);
  k_scatter2<<<(N + E + 255) / 256, 256, 0, stream>>>(zone, N, erow, ecol, E,
                                                      startb, cursor, perm, estartb, ecursor, erow_s);
  k_fused<<<1024, 256, 0, stream>>>(x, perm, startb, A, cvec, Xagg, denom, R);
  k_epilogue<<<(R + 7) / 8, 256, 0, stream>>>(Xagg, denom, qvec, Wv, bv, Wo, bo, Wg, hbuf, R);
  k_gcn<<<(R + 3) / 4, 256, 0, stream>>>(estartb, erow_s, dinv, hbuf, bg, pw, out, R);
}